// Round 7
// baseline (271.554 us; speedup 1.0000x reference)
//
#include <hip/hip_runtime.h>
#include <math.h>

#define HH 96
#define WW 96
#define HW 9216
#define CIN 128
#define COUT 256

typedef _Float16 f16;
typedef _Float16 f16x2 __attribute__((ext_vector_type(2)));
typedef _Float16 f16x8 __attribute__((ext_vector_type(8)));
typedef __attribute__((ext_vector_type(4))) float f32x4;

static __device__ __forceinline__ unsigned short f2h(float f) {
  union { f16 h; unsigned short u; } v; v.h = (f16)f; return v.u;
}

// ---------------- fused prep kernel (R5/R6, measured + passed) ----------------
__global__ __launch_bounds__(256) void k_prep(const float* __restrict__ x,
                                              const float* __restrict__ offw,
                                              const float* __restrict__ modw,
                                              const float* __restrict__ wgt,
                                              unsigned short* __restrict__ xTh,
                                              unsigned short* __restrict__ wAbF,
                                              unsigned short* __restrict__ wTtF) {
  __shared__ float tile[32][129];
  int bid = blockIdx.x;
  int t = threadIdx.x;
  if (bid < 1152) {
    int wseg = bid % 3, h = (bid / 3) % 96, b = bid / 288;
    int wl = t & 31, cg = t >> 5;
    const float* xp = x + ((size_t)(b * 128 + cg) * 96 + h) * 96 + wseg * 32 + wl;
#pragma unroll
    for (int i = 0; i < 16; ++i)
      tile[wl][cg + 8 * i] = xp[(size_t)8 * i * HW];
    __syncthreads();
    int cl = t & 127, wg = t >> 7;
    unsigned short* op = xTh + (((size_t)(b * 96 + h) * 96) + wseg * 32) * 128 + cl;
#pragma unroll
    for (int i = 0; i < 16; ++i)
      op[(size_t)(wg + 2 * i) * 128] = f2h(tile[wg + 2 * i][cl]);
  } else if (bid < 1296) {
    int i = (bid - 1152) * 256 + t;
    if (i < 9 * 2 * 4 * 512) {
      int j = i & 7;
      int l = (i >> 3) & 63;
      int ks = (i >> 9) & 3;
      int ng = i >> 11;             // kpos*2 + n16
      int kpos = ng >> 1, n16 = ng & 1;
      int n = n16 * 16 + (l & 15);
      int c = ks * 32 + (l >> 4) * 8 + j;
      float v = 0.f;
      if (n < 18) v = offw[n * 1152 + c * 9 + kpos];
      else if (n < 27) v = modw[(n - 18) * 1152 + c * 9 + kpos];
      wAbF[i] = f2h(v);
    }
  } else {
    int i = (bid - 1296) * 256 + t;
    if (i < 9 * 16 * 4 * 512) {
      int j = i & 7;
      int l = (i >> 3) & 63;
      int ks = (i >> 9) & 3;
      int ng = i >> 11;             // kpos*16 + n16
      int kpos = ng >> 4, n16 = ng & 15;
      int n = n16 * 16 + (l & 15);
      int c = ks * 32 + (l >> 4) * 8 + j;
      wTtF[i] = f2h(wgt[n * 1152 + c * 9 + kpos]);
    }
  }
}

// ---------------- fused main kernel: barrier-free wave-private K-loop ----------------
// 576 blocks x 256 thr (4 waves). Wave owns 16 px x 256 N; block covers 64 px.
// Prologue (R6, measured): offset/mask conv -> om_lds; ONE barrier after it.
// Main loop: A gathered direct-to-fragment in registers (16 uint4/kpos/lane,
// zero redundancy), B direct-to-register from wTtF (L1/L2). 64 MFMAs per kpos
// per wave. Next-kpos gather issued before the MFMA sweep (latency hidden).
__global__ __launch_bounds__(256, 2) void k_main(const unsigned short* __restrict__ xTh,
                                                 const unsigned short* __restrict__ wAbF,
                                                 const unsigned short* __restrict__ wTtF,
                                                 const float* __restrict__ offb,
                                                 const float* __restrict__ modb,
                                                 const float* __restrict__ bias,
                                                 float* __restrict__ out) {
  __shared__ float om_lds[27 * 65];      // 7020 B
  __shared__ float ez[4 * 16 * 65];      // 16640 B per-wave [16][65] zones

  int t = threadIdx.x;
  int l = t & 63, w = t >> 6;
  int lm = l & 15, lq = l >> 4;
  int raw = blockIdx.x;
  int bid = (raw & 7) * 72 + (raw >> 3);   // XCD swizzle (576 = 8*72)
  int pix0 = bid * 64;
  int b = pix0 / HW;
  int posim0 = pix0 % HW;
  int ibase = b * HW;

  // ======== offset/mask prologue (R6, measured working) ========
  {
    int prow = pix0 + w * 16 + lm;
    int pimo = prow % HW;
    int hoo = pimo / 96, woo = pimo % 96;
    f32x4 acco[2];
    acco[0] = (f32x4){0.f, 0.f, 0.f, 0.f};
    acco[1] = (f32x4){0.f, 0.f, 0.f, 0.f};
    const f16x8 zv = {0, 0, 0, 0, 0, 0, 0, 0};
#pragma unroll 1
    for (int kpos = 0; kpos < 9; ++kpos) {
      int dyr = kpos / 3 - 1, dxr = kpos % 3 - 1;
      bool valid = ((unsigned)(hoo + dyr) < 96u) && ((unsigned)(woo + dxr) < 96u);
      int srow = valid ? (prow + dyr * 96 + dxr) : prow;
      const unsigned short* ap = xTh + (size_t)srow * 128 + lq * 8;
      const unsigned short* bp = wAbF + (size_t)(kpos * 8) * 512 + l * 8;
#pragma unroll
      for (int ks = 0; ks < 4; ++ks) {
        f16x8 af = valid ? *(const f16x8*)(ap + ks * 32) : zv;
        f16x8 bf0 = *(const f16x8*)(bp + (size_t)ks * 512);
        f16x8 bf1 = *(const f16x8*)(bp + (size_t)(4 + ks) * 512);
        acco[0] = __builtin_amdgcn_mfma_f32_16x16x32_f16(af, bf0, acco[0], 0, 0, 0);
        acco[1] = __builtin_amdgcn_mfma_f32_16x16x32_f16(af, bf1, acco[1], 0, 0, 0);
      }
    }
#pragma unroll
    for (int nt = 0; nt < 2; ++nt) {
      int n = nt * 16 + lm;
      if (n < 27) {
        float bv = (n < 18) ? offb[n] : modb[n - 18];
#pragma unroll
        for (int r = 0; r < 4; ++r) {
          float v = acco[nt][r] + bv;
          if (n >= 18) v = 1.f / (1.f + expf(-v));
          om_lds[n * 65 + w * 16 + lq * 4 + r] = v;
        }
      }
    }
  }
  __syncthreads();   // the ONLY block-wide barrier

  // ======== barrier-free main loop ========
  int mypx = w * 16 + lm;                  // wave-private pixel (row of A-frag)
  int pim = (pix0 + mypx) % HW;
  int ho = pim / 96, wo = pim % 96;

  f32x4 acc[16];
#pragma unroll
  for (int i = 0; i < 16; ++i) acc[i] = (f32x4){0.f, 0.f, 0.f, 0.f};

  int o00 = 0, o01 = 0, o10 = 0, o11 = 0;
  f16x2 wp00, wp01, wp10, wp11;
  uint4 q00[4], q01[4], q10[4], q11[4];    // in-flight corners, one octet per ks

  auto geom_issue = [&](int kp) {
    float dy = om_lds[(2 * kp) * 65 + mypx];
    float dx = om_lds[(2 * kp + 1) * 65 + mypx];
    float mk = om_lds[(18 + kp) * 65 + mypx];
    float py = (float)(ho - 1 + kp / 3) + dy;
    float pxf = (float)(wo - 1 + kp % 3) + dx;
    float fy = floorf(py), fx = floorf(pxf);
    int y0 = (int)fy, x0 = (int)fx;
    float ly = py - fy, lx = pxf - fx;
    float w00 = (1.f - ly) * (1.f - lx), w01 = (1.f - ly) * lx;
    float w10 = ly * (1.f - lx),         w11 = ly * lx;
    bool vy0 = (unsigned)y0 < 96u, vy1 = (unsigned)(y0 + 1) < 96u;
    bool vx0 = (unsigned)x0 < 96u, vx1 = (unsigned)(x0 + 1) < 96u;
    w00 = (vy0 && vx0) ? w00 * mk : 0.f;
    w01 = (vy0 && vx1) ? w01 * mk : 0.f;
    w10 = (vy1 && vx0) ? w10 * mk : 0.f;
    w11 = (vy1 && vx1) ? w11 * mk : 0.f;
    int y0c = min(max(y0, 0), 95), y1c = min(max(y0 + 1, 0), 95);
    int x0c = min(max(x0, 0), 95), x1c = min(max(x0 + 1, 0), 95);
    o00 = (ibase + y0c * 96 + x0c) * 128;
    o01 = (ibase + y0c * 96 + x1c) * 128;
    o10 = (ibase + y1c * 96 + x0c) * 128;
    o11 = (ibase + y1c * 96 + x1c) * 128;
    f16 h00 = (f16)w00, h01 = (f16)w01, h10 = (f16)w10, h11 = (f16)w11;
    wp00 = (f16x2){h00, h00}; wp01 = (f16x2){h01, h01};
    wp10 = (f16x2){h10, h10}; wp11 = (f16x2){h11, h11};
#pragma unroll
    for (int ks = 0; ks < 4; ++ks) {
      int cc = ks * 32 + lq * 8;
      q00[ks] = *(const uint4*)(xTh + o00 + cc);
      q01[ks] = *(const uint4*)(xTh + o01 + cc);
      q10[ks] = *(const uint4*)(xTh + o10 + cc);
      q11[ks] = *(const uint4*)(xTh + o11 + cc);
    }
  };

  geom_issue(0);

#pragma unroll 1
  for (int kpos = 0; kpos < 9; ++kpos) {
    // interp current corners -> 4 A-frags (frees q for next issue)
    f16x8 af[4];
    f16x2 cw00 = wp00, cw01 = wp01, cw10 = wp10, cw11 = wp11;
#pragma unroll
    for (int ks = 0; ks < 4; ++ks) {
      union { uint4 u; f16x2 h[4]; } a0, a1, a2, a3;
      a0.u = q00[ks]; a1.u = q01[ks]; a2.u = q10[ks]; a3.u = q11[ks];
      union { f16x8 v; f16x2 h[4]; } r;
#pragma unroll
      for (int j = 0; j < 4; ++j)
        r.h[j] = a0.h[j] * cw00 + a1.h[j] * cw01 + a2.h[j] * cw10 + a3.h[j] * cw11;
      af[ks] = r.v;
    }
    // issue next kpos gather early (hides under the 64-MFMA sweep)
    if (kpos < 8) geom_issue(kpos + 1);
    // MFMA sweep: 16 n-frags x 4 k-slices, B direct from L1/L2
    const unsigned short* bpk = wTtF + (size_t)(kpos * 64) * 512 + l * 8;
#pragma unroll
    for (int nt = 0; nt < 16; ++nt) {
#pragma unroll
      for (int ks = 0; ks < 4; ++ks) {
        f16x8 bf = *(const f16x8*)(bpk + (size_t)(nt * 4 + ks) * 512);
        acc[nt] = __builtin_amdgcn_mfma_f32_16x16x32_f16(af[ks], bf, acc[nt], 0, 0, 0);
      }
    }
  }

  // ======== epilogue: wave-private transpose zones (no barriers) ========
  float bias_v[16];
#pragma unroll
  for (int nt = 0; nt < 16; ++nt) bias_v[nt] = bias[nt * 16 + lm];
  float* z = ez + w * (16 * 65);
  int pxr = l & 15, ng = l >> 4;
#pragma unroll
  for (int chunk = 0; chunk < 4; ++chunk) {
#pragma unroll
    for (int j = 0; j < 4; ++j) {
      int nt = chunk * 4 + j;
#pragma unroll
      for (int r = 0; r < 4; ++r)
        z[(lq * 4 + r) * 65 + j * 16 + lm] = acc[nt][r] + bias_v[nt];
    }
#pragma unroll
    for (int s = 0; s < 16; ++s) {
      int nl = s * 4 + ng;          // n within chunk, 0..63
      out[((size_t)(b * COUT + chunk * 64 + nl)) * HW + posim0 + w * 16 + pxr] =
          z[pxr * 65 + nl];
    }
  }
}

extern "C" void kernel_launch(void* const* d_in, const int* in_sizes, int n_in,
                              void* d_out, int out_size, void* d_ws, size_t ws_size,
                              hipStream_t stream) {
  const float* x      = (const float*)d_in[0];
  const float* weight = (const float*)d_in[1];
  const float* bias   = (const float*)d_in[2];
  const float* offw   = (const float*)d_in[3];
  const float* offb   = (const float*)d_in[4];
  const float* modw   = (const float*)d_in[5];
  const float* modb   = (const float*)d_in[6];
  float* out = (float*)d_out;
  float* ws = (float*)d_ws;

  unsigned short* xTh  = (unsigned short*)ws;                      // 4718592 us
  unsigned short* wTtF = (unsigned short*)(ws + 2359296);          // 294912 us
  unsigned short* wAbF = (unsigned short*)(ws + 2359296 + 147456); // 36864 us

  k_prep<<<2448, 256, 0, stream>>>(x, offw, modw, weight, xTh, wAbF, wTtF);
  k_main<<<576, 256, 0, stream>>>(xTh, wAbF, wTtF, offb, modb, bias, out);
}

// Round 8
// 149.586 us; speedup vs baseline: 1.8154x; 1.8154x over previous
//
#include <hip/hip_runtime.h>
#include <math.h>

#define HH 96
#define WW 96
#define HW 9216
#define CIN 128
#define COUT 256

typedef _Float16 f16;
typedef _Float16 f16x2 __attribute__((ext_vector_type(2)));
typedef _Float16 f16x8 __attribute__((ext_vector_type(8)));
typedef __attribute__((ext_vector_type(4))) float f32x4;

static __device__ __forceinline__ unsigned short f2h(float f) {
  union { f16 h; unsigned short u; } v; v.h = (f16)f; return v.u;
}

// ---------------- fused prep kernel (R5/R6, measured + passed) ----------------
__global__ __launch_bounds__(256) void k_prep(const float* __restrict__ x,
                                              const float* __restrict__ offw,
                                              const float* __restrict__ modw,
                                              const float* __restrict__ wgt,
                                              unsigned short* __restrict__ xTh,
                                              unsigned short* __restrict__ wAbF,
                                              unsigned short* __restrict__ wTtF) {
  __shared__ float tile[32][129];
  int bid = blockIdx.x;
  int t = threadIdx.x;
  if (bid < 1152) {
    int wseg = bid % 3, h = (bid / 3) % 96, b = bid / 288;
    int wl = t & 31, cg = t >> 5;
    const float* xp = x + ((size_t)(b * 128 + cg) * 96 + h) * 96 + wseg * 32 + wl;
#pragma unroll
    for (int i = 0; i < 16; ++i)
      tile[wl][cg + 8 * i] = xp[(size_t)8 * i * HW];
    __syncthreads();
    int cl = t & 127, wg = t >> 7;
    unsigned short* op = xTh + (((size_t)(b * 96 + h) * 96) + wseg * 32) * 128 + cl;
#pragma unroll
    for (int i = 0; i < 16; ++i)
      op[(size_t)(wg + 2 * i) * 128] = f2h(tile[wg + 2 * i][cl]);
  } else if (bid < 1296) {
    int i = (bid - 1152) * 256 + t;
    if (i < 9 * 2 * 4 * 512) {
      int j = i & 7;
      int l = (i >> 3) & 63;
      int ks = (i >> 9) & 3;
      int ng = i >> 11;             // kpos*2 + n16
      int kpos = ng >> 1, n16 = ng & 1;
      int n = n16 * 16 + (l & 15);
      int c = ks * 32 + (l >> 4) * 8 + j;
      float v = 0.f;
      if (n < 18) v = offw[n * 1152 + c * 9 + kpos];
      else if (n < 27) v = modw[(n - 18) * 1152 + c * 9 + kpos];
      wAbF[i] = f2h(v);
    }
  } else {
    int i = (bid - 1296) * 256 + t;
    if (i < 9 * 16 * 4 * 512) {
      int j = i & 7;
      int l = (i >> 3) & 63;
      int ks = (i >> 9) & 3;
      int ng = i >> 11;             // kpos*16 + n16
      int kpos = ng >> 4, n16 = ng & 15;
      int n = n16 * 16 + (l & 15);
      int c = ks * 32 + (l >> 4) * 8 + j;
      wTtF[i] = f2h(wgt[n * 1152 + c * 9 + kpos]);
    }
  }
}

// ---------------- fused main kernel ----------------
// 1152 blocks x 256 thr (4 waves). M-tile 32 px, N=256 (wave owns 64n), K=1152.
// Prologue (R5, measured): offset/mask conv -> om_lds.
// A-stage remap (NEW): thread t owns px=t>>3, ch-octet slots (t&7)+{0,8}.
// Within one 64-lane load instruction: 8 px-rows x 128B dense = 8 cache lines
// (was 64 scattered lines with px=t&31 mapping) -> 8x fewer TCP transactions.
// Full 128-ch phase per kpos (halves merged): 18 barriers total, 32 MFMA/phase/wave.
// B direct-to-register from fragment-ordered wTtF, wave-partitioned (R4-proven).
__global__ __launch_bounds__(256) void k_main(const unsigned short* __restrict__ xTh,
                                              const unsigned short* __restrict__ wAbF,
                                              const unsigned short* __restrict__ wTtF,
                                              const float* __restrict__ offb,
                                              const float* __restrict__ modb,
                                              const float* __restrict__ bias,
                                              float* __restrict__ out) {
  __shared__ __align__(16) unsigned short Ab[32 * 136];  // 8704 B (272B row, mod128=16)
  __shared__ float om_lds[27 * 33];                      // 3564 B
  __shared__ float ez[4 * 1040];                         // 16640 B (wave zones 16x65)

  int t = threadIdx.x;
  int l = t & 63, w = t >> 6;
  int lm = l & 15, lq = l >> 4;
  int raw = blockIdx.x;
  int bid = (raw & 7) * 144 + (raw >> 3);   // XCD swizzle (1152 = 8*144)
  int pix0 = bid * 32;
  int b = pix0 / HW;
  int posim0 = pix0 % HW;
  int ibase = b * HW;

  // ======== offset/mask conv prologue (R5 verbatim, measured) ========
  {
    int mh = w & 1, n16o = w >> 1;
    int prow = pix0 + mh * 16 + lm;
    int pimo = prow % HW;
    int hoo = pimo / 96, woo = pimo % 96;
    f32x4 acco = (f32x4){0.f, 0.f, 0.f, 0.f};
    const f16x8 zv = {0, 0, 0, 0, 0, 0, 0, 0};
#pragma unroll 1
    for (int kpos = 0; kpos < 9; ++kpos) {
      int dyr = kpos / 3 - 1, dxr = kpos % 3 - 1;
      bool valid = ((unsigned)(hoo + dyr) < 96u) && ((unsigned)(woo + dxr) < 96u);
      int srow = valid ? (prow + dyr * 96 + dxr) : prow;
      const unsigned short* ap = xTh + (size_t)srow * 128 + lq * 8;
      const unsigned short* bp = wAbF + (size_t)((kpos * 2 + n16o) * 4) * 512 + l * 8;
#pragma unroll
      for (int ks = 0; ks < 4; ++ks) {
        f16x8 af = valid ? *(const f16x8*)(ap + ks * 32) : zv;
        f16x8 bf = *(const f16x8*)(bp + (size_t)ks * 512);
        acco = __builtin_amdgcn_mfma_f32_16x16x32_f16(af, bf, acco, 0, 0, 0);
      }
    }
    int n = n16o * 16 + lm;
    if (n < 27) {
      float bv = (n < 18) ? offb[n] : modb[n - 18];
#pragma unroll
      for (int r = 0; r < 4; ++r) {
        float v = acco[r] + bv;
        if (n >= 18) v = 1.f / (1.f + expf(-v));
        om_lds[n * 33 + mh * 16 + lq * 4 + r] = v;
      }
    }
  }
  __syncthreads();

  // ======== main deformable GEMM ========
  int pxo = t >> 3;                 // staging pixel owned by this thread (0..31)
  int sc8 = t & 7;                  // ch-octet slot base (slots sc8 and sc8+8)
  int pimS = (pix0 + pxo) % HW;
  int hoS = pimS / 96, woS = pimS % 96;

  f32x4 acc[2][4];
#pragma unroll
  for (int i = 0; i < 2; ++i)
#pragma unroll
    for (int j = 0; j < 4; ++j)
      acc[i][j] = (f32x4){0.f, 0.f, 0.f, 0.f};

  for (int kpos = 0; kpos < 9; ++kpos) {
    // geometry for owned pixel (8x redundant across the 8 threads sharing pxo)
    float dy = om_lds[(2 * kpos) * 33 + pxo];
    float dx = om_lds[(2 * kpos + 1) * 33 + pxo];
    float mk = om_lds[(18 + kpos) * 33 + pxo];
    float py = (float)(hoS - 1 + kpos / 3) + dy;
    float pxf = (float)(woS - 1 + kpos % 3) + dx;
    float fy = floorf(py), fx = floorf(pxf);
    int y0 = (int)fy, x0 = (int)fx;
    float ly = py - fy, lx = pxf - fx;
    float w00 = (1.f - ly) * (1.f - lx), w01 = (1.f - ly) * lx;
    float w10 = ly * (1.f - lx),         w11 = ly * lx;
    bool vy0 = (unsigned)y0 < 96u, vy1 = (unsigned)(y0 + 1) < 96u;
    bool vx0 = (unsigned)x0 < 96u, vx1 = (unsigned)(x0 + 1) < 96u;
    w00 = (vy0 && vx0) ? w00 * mk : 0.f;
    w01 = (vy0 && vx1) ? w01 * mk : 0.f;
    w10 = (vy1 && vx0) ? w10 * mk : 0.f;
    w11 = (vy1 && vx1) ? w11 * mk : 0.f;
    int y0c = min(max(y0, 0), 95), y1c = min(max(y0 + 1, 0), 95);
    int x0c = min(max(x0, 0), 95), x1c = min(max(x0 + 1, 0), 95);
    int ofs[4];
    ofs[0] = (ibase + y0c * 96 + x0c) * 128;
    ofs[1] = (ibase + y0c * 96 + x1c) * 128;
    ofs[2] = (ibase + y1c * 96 + x0c) * 128;
    ofs[3] = (ibase + y1c * 96 + x1c) * 128;
    f16 h00 = (f16)w00, h01 = (f16)w01, h10 = (f16)w10, h11 = (f16)w11;
    f16x2 wp[4];
    wp[0] = (f16x2){h00, h00}; wp[1] = (f16x2){h01, h01};
    wp[2] = (f16x2){h10, h10}; wp[3] = (f16x2){h11, h11};

    // issue 8 dense corner loads (8 lines/instruction) BEFORE barrier:
    // latency overlaps the barrier wait for other waves' MFMA completion
    uint4 q[4][2];
#pragma unroll
    for (int c = 0; c < 4; ++c)
#pragma unroll
      for (int it = 0; it < 2; ++it)
        q[c][it] = *(const uint4*)(xTh + ofs[c] + (sc8 + 8 * it) * 8);

    __syncthreads();   // previous-kpos MFMA readers done with Ab
    // interp + write own octets
#pragma unroll
    for (int it = 0; it < 2; ++it) {
      union { uint4 u; f16x2 h[4]; } a0, a1, a2, a3;
      a0.u = q[0][it]; a1.u = q[1][it]; a2.u = q[2][it]; a3.u = q[3][it];
      union { f16x8 v; f16x2 h[4]; } r;
#pragma unroll
      for (int j = 0; j < 4; ++j)
        r.h[j] = a0.h[j] * wp[0] + a1.h[j] * wp[1] + a2.h[j] * wp[2] + a3.h[j] * wp[3];
      *(f16x8*)(Ab + pxo * 136 + (sc8 + 8 * it) * 8) = r.v;
    }
    __syncthreads();   // A tile ready

    // MFMA sweep: 4 ks x 2 mt x 4 nt = 32 MFMAs/wave; B wave-partitioned
#pragma unroll
    for (int ks = 0; ks < 4; ++ks) {
      f16x8 af[2], bfv[4];
#pragma unroll
      for (int mt = 0; mt < 2; ++mt)
        af[mt] = *(const f16x8*)(Ab + (mt * 16 + lm) * 136 + ks * 32 + lq * 8);
      const unsigned short* bp =
          wTtF + (size_t)((kpos * 16 + w * 4) * 4 + ks) * 512 + l * 8;
#pragma unroll
      for (int nt = 0; nt < 4; ++nt)
        bfv[nt] = *(const f16x8*)(bp + (size_t)nt * 4 * 512);
#pragma unroll
      for (int mt = 0; mt < 2; ++mt)
#pragma unroll
        for (int nt = 0; nt < 4; ++nt)
          acc[mt][nt] = __builtin_amdgcn_mfma_f32_16x16x32_f16(af[mt], bfv[nt], acc[mt][nt], 0, 0, 0);
    }
  }

  // ======== epilogue: per-wave 16x64 transpose zones (R5 verbatim, measured) ========
  float bias_v[4];
#pragma unroll
  for (int nt = 0; nt < 4; ++nt) bias_v[nt] = bias[w * 64 + nt * 16 + lm];
  float* z = ez + w * 1040;   // [16][65]
#pragma unroll
  for (int mt = 0; mt < 2; ++mt) {
    __syncthreads();
#pragma unroll
    for (int nt = 0; nt < 4; ++nt)
#pragma unroll
      for (int r = 0; r < 4; ++r)
        z[(lq * 4 + r) * 65 + nt * 16 + lm] = acc[mt][nt][r] + bias_v[nt];
    __syncthreads();
    int pxr = l & 15;
    int nb = l >> 4;
#pragma unroll
    for (int s = 0; s < 16; ++s) {
      int n = nb + 4 * s;
      out[((size_t)(b * COUT + w * 64 + n)) * HW + posim0 + mt * 16 + pxr] = z[pxr * 65 + n];
    }
  }
}

extern "C" void kernel_launch(void* const* d_in, const int* in_sizes, int n_in,
                              void* d_out, int out_size, void* d_ws, size_t ws_size,
                              hipStream_t stream) {
  const float* x      = (const float*)d_in[0];
  const float* weight = (const float*)d_in[1];
  const float* bias   = (const float*)d_in[2];
  const float* offw   = (const float*)d_in[3];
  const float* offb   = (const float*)d_in[4];
  const float* modw   = (const float*)d_in[5];
  const float* modb   = (const float*)d_in[6];
  float* out = (float*)d_out;
  float* ws = (float*)d_ws;

  unsigned short* xTh  = (unsigned short*)ws;                      // 4718592 us
  unsigned short* wTtF = (unsigned short*)(ws + 2359296);          // 294912 us
  unsigned short* wAbF = (unsigned short*)(ws + 2359296 + 147456); // 36864 us

  k_prep<<<2448, 256, 0, stream>>>(x, offw, modw, weight, xTh, wAbF, wTtF);
  k_main<<<1152, 256, 0, stream>>>(xTh, wAbF, wTtF, offb, modb, bias, out);
}